// Round 14
// baseline (435.235 us; speedup 1.0000x reference)
//
#include <hip/hip_runtime.h>
#include <math.h>

#define BATCH 8
#define NPTS 2048
#define MPTS 2048
#define TPB 256                       // 4 waves
#define RPB 16                        // rows per block
#define KC 8                          // columns per thread: 2048/256
#define RPR 4                         // rows per round
#define NRND (RPB/RPR)                // 4 rounds
#define CHUNKS (NPTS/RPB)             // 128
#define NBLK (BATCH*CHUNKS)           // 1024

// Persistent state (re-initialized every kernel_launch -> deterministic).
// colsum rotation: level l reads g_cbuf[l%3], accumulates into g_cbuf[(l+1)%3],
// zeroes g_cbuf[(l+2)%3]. remainr ping-pongs g_rbuf[l&1] -> g_rbuf[(l+1)&1].
// rr/zero global writes gated to chunk==0 (identical values across blocks).
__device__ float  g_remainl[BATCH*NPTS];
__device__ float  g_s[BATCH*NPTS];
__device__ float  g_rbuf[2][BATCH*MPTS];
__device__ float  g_cbuf[3][BATCH*MPTS];
__device__ float4 g_gt4[BATCH*MPTS];   // (x, y, z, |c|^2)
__device__ float4 g_gen4[BATCH*NPTS];  // (-2x, -2y, -2z, |g|^2)
__device__ float  g_cost;

#if __has_builtin(__builtin_amdgcn_exp2f)
#define EXP2(x) __builtin_amdgcn_exp2f(x)
#else
#define EXP2(x) exp2f(x)
#endif
#if __has_builtin(__builtin_amdgcn_sqrtf)
#define FSQRT(x) __builtin_amdgcn_sqrtf(x)
#else
#define FSQRT(x) sqrtf(x)
#endif
#if __has_builtin(__builtin_amdgcn_rcpf)
#define RCP(x) __builtin_amdgcn_rcpf(x)
#else
#define RCP(x) (1.0f/(x))
#endif

template<int CTRL>
__device__ __forceinline__ float dpp_add(float x) {
  const int y = __builtin_amdgcn_update_dpp(0, __float_as_int(x),
                                            CTRL, 0xF, 0xF, true);
  return x + __int_as_float(y);
}
// 4 DPP steps -> every lane holds its 16-lane group's sum. Pure VALU.
__device__ __forceinline__ void dpp16_4(float& a, float& b, float& c, float& d) {
  a = dpp_add<0xB1>(a);  b = dpp_add<0xB1>(b);
  c = dpp_add<0xB1>(c);  d = dpp_add<0xB1>(d);
  a = dpp_add<0x4E>(a);  b = dpp_add<0x4E>(b);
  c = dpp_add<0x4E>(c);  d = dpp_add<0x4E>(d);
  a = dpp_add<0x141>(a); b = dpp_add<0x141>(b);
  c = dpp_add<0x141>(c); d = dpp_add<0x141>(d);
  a = dpp_add<0x140>(a); b = dpp_add<0x140>(b);
  c = dpp_add<0x140>(c); d = dpp_add<0x140>(d);
}
__device__ __forceinline__ float wsum_step1(float a) {
  a = dpp_add<0xB1>(a); a = dpp_add<0x4E>(a);
  a = dpp_add<0x141>(a); a = dpp_add<0x140>(a);
  a += __shfl_xor(a, 16); a += __shfl_xor(a, 32);
  return a;
}

#define D2(rd, k) fmaf(rd.x, cx[k], fmaf(rd.y, cy[k],                      \
                   fmaf(rd.z, cz[k], rd.w + rc2[k])))

// init + point prep (SoA float4 with precomputed norms).
__global__ __launch_bounds__(256) void k_init(const float* __restrict__ gen,
                                              const float* __restrict__ gt) {
  const int i = blockIdx.x*256 + threadIdx.x;   // 64 x 256 = 16384 = B*N
  g_cbuf[0][i] = 0.f;
  g_cbuf[1][i] = 0.f;
  g_rbuf[0][i] = 1.f;
  const float tx = gt[i*3], ty = gt[i*3+1], tz = gt[i*3+2];
  g_gt4[i] = make_float4(tx, ty, tz, tx*tx + ty*ty + tz*tz);
  const float px = gen[i*3], py = gen[i*3+1], pz = gen[i*3+2];
  g_gen4[i] = make_float4(-2.f*px, -2.f*py, -2.f*pz, px*px + py*py + pz*pz);
  if (i == 0) g_cost = 0.f;
}

// A-part of level 0 (remainl = remainr = 1): computes s(0), colsum(0).
// 4 rows per round, 1 barrier per round; 16-lane DPP sums -> LDS atomics
// into a triple-buffered accumulator (zero/add/read in separate windows).
__global__ __launch_bounds__(TPB) void k_a0(float c1) {
  const int blk = blockIdx.x, b = blk >> 7, chunk = blk & (CHUNKS-1);
  const int t = threadIdx.x, lane = t & 63, wave = t >> 6;
  const int rowbase = b*NPTS + chunk*RPB;
  __shared__ float4 rowdat[RPB];
  __shared__ float  redf[3][RPR];
  float cx[KC], cy[KC], cz[KC], rc2[KC];
  #pragma unroll
  for (int k = 0; k < KC; ++k) {
    const float4 q = g_gt4[b*MPTS + t + TPB*k];
    cx[k] = q.x; cy[k] = q.y; cz[k] = q.z; rc2[k] = q.w;
  }
  if (t < RPB) {
    rowdat[t] = g_gen4[rowbase + t];
    g_remainl[rowbase + t] = 1.0f;
  }
  if (t < 3*RPR) ((float*)redf)[t] = 0.f;
  __syncthreads();
  float colacc[KC];
  #pragma unroll
  for (int k = 0; k < KC; ++k) colacc[k] = 0.f;
  float w[RPR][KC];

#define A0_ELEM(RR)                                                        \
  {                                                                        \
    float s1[RPR];                                                         \
    _Pragma("unroll")                                                      \
    for (int j = 0; j < RPR; ++j) {                                        \
      const float4 rd = rowdat[RPR*(RR) + j];                              \
      float a1 = 0.f;                                                      \
      _Pragma("unroll")                                                    \
      for (int k = 0; k < KC; ++k) {                                       \
        const float e = EXP2(c1*D2(rd, k));                                \
        w[j][k] = e; a1 += e;                                              \
      }                                                                    \
      s1[j] = a1;                                                          \
    }                                                                      \
    dpp16_4(s1[0], s1[1], s1[2], s1[3]);                                   \
    if ((lane & 15) == 0) {                                                \
      float* rb = redf[(RR) % 3];                                          \
      atomicAdd(&rb[0], s1[0]); atomicAdd(&rb[1], s1[1]);                  \
      atomicAdd(&rb[2], s1[2]); atomicAdd(&rb[3], s1[3]);                  \
    }                                                                      \
  }

  A0_ELEM(0)
  #pragma unroll 1
  for (int r = 0; r < NRND; ++r) {
    __syncthreads();
    float scn[RPR];
    #pragma unroll
    for (int j = 0; j < RPR; ++j)
      scn[j] = RCP(redf[r % 3][j] + 1e-9f);    // remainl = 1
    if (t < RPR) redf[(r + 2) % 3][t] = 0.f;
    if (t == 0) {
      #pragma unroll
      for (int j = 0; j < RPR; ++j) g_s[rowbase + RPR*r + j] = scn[j];
    }
    #pragma unroll
    for (int k = 0; k < KC; ++k) {
      float acc = colacc[k];
      #pragma unroll
      for (int j = 0; j < RPR; ++j) acc = fmaf(w[j][k], scn[j], acc);
      colacc[k] = acc;
    }
    if (r + 1 < NRND) A0_ELEM(r + 1)
  }
#undef A0_ELEM
  #pragma unroll
  for (int k = 0; k < KC; ++k)
    atomicAdd(&g_cbuf[0][b*MPTS + t + TPB*k], colacc[k]);   // remainr == 1
  (void)wave;
}

// Fused [k_cols(l)] + C(level l) + A(level l+1); 4 rows/round, 4 rounds.
// eq = exp2(cq*d2) is next level's exp; e1 = (eq^2)^2 (c1 = 4*cq exactly).
// LAST (l==8): next level coeff is 0 -> eq = 1.
template<bool LAST>
__global__ __launch_bounds__(TPB) void k_ca(float c1, float cq, int l) {
  const int blk = blockIdx.x, b = blk >> 7, chunk = blk & (CHUNKS-1);
  const int t = threadIdx.x, lane = t & 63, wave = t >> 6;
  const int rowbase = b*NPTS + chunk*RPB;
  const float* __restrict__ cs_in = g_cbuf[l % 3];
  float* __restrict__ cs_out  = g_cbuf[(l+1) % 3];
  float* __restrict__ cs_zero = g_cbuf[(l+2) % 3];
  const float* __restrict__ rr_in = g_rbuf[l & 1];
  float* __restrict__ rr_out = g_rbuf[(l+1) & 1];
  __shared__ float4 rowdat[RPB];
  __shared__ float  sc_s[RPB], rl_s[RPB];
  __shared__ float  redf[3][2*RPR];    // per round: s1[0..3], rs[0..3]
  __shared__ float  cred[4];
  // column stage + folded k_cols (global writes gated to chunk==0)
  float cx[KC], cy[KC], cz[KC], rc2[KC], pp[KC], rrn[KC];
  #pragma unroll
  for (int k = 0; k < KC; ++k) {
    const int m = b*MPTS + t + TPB*k;
    const float4 q = g_gt4[m];
    cx[k] = q.x; cy[k] = q.y; cz[k] = q.z; rc2[k] = q.w;
    const float cs = cs_in[m], rrv = rr_in[m];
    const float ratio = fminf(rrv / (cs + 1e-9f), 1.0f);
    pp[k]  = rrv*ratio;
    rrn[k] = fmaxf(rrv - cs*ratio, 0.0f);
    if (chunk == 0) { rr_out[m] = rrn[k]; cs_zero[m] = 0.0f; }
  }
  if (t < RPB) {
    rowdat[t] = g_gen4[rowbase + t];
    sc_s[t] = g_s[rowbase + t];
    rl_s[t] = g_remainl[rowbase + t];
  }
  if (t < 3*2*RPR) ((float*)redf)[t] = 0.f;
  __syncthreads();
  float colacc[KC];
  #pragma unroll
  for (int k = 0; k < KC; ++k) colacc[k] = 0.f;
  float costacc = 0.f;
  float w[RPR][KC];

#define CA_ELEM(RR)                                                        \
  {                                                                        \
    float s1[RPR], rs[RPR];                                                \
    _Pragma("unroll")                                                      \
    for (int j = 0; j < RPR; ++j) {                                        \
      const float4 rd = rowdat[RPR*(RR) + j];                              \
      float a1 = 0.f, a2 = 0.f, ar = 0.f;                                  \
      _Pragma("unroll")                                                    \
      for (int k = 0; k < KC; ++k) {                                       \
        const float d2 = D2(rd, k);                                        \
        float e1, wq;                                                      \
        if (LAST) { e1 = EXP2(c1*d2); wq = rrn[k]; }                       \
        else { const float eq = EXP2(cq*d2); const float q2 = eq*eq;       \
               e1 = q2*q2; wq = eq*rrn[k]; }                               \
        w[j][k] = wq; ar += wq;                                            \
        const float u = e1*pp[k];                                          \
        a1 += u;                                                           \
        a2 = fmaf(u, FSQRT(fmaxf(d2, 1e-20f)), a2);                        \
      }                                                                    \
      s1[j] = a1; rs[j] = ar;                                              \
      costacc = fmaf(sc_s[RPR*(RR) + j], a2, costacc);                     \
    }                                                                      \
    dpp16_4(s1[0], s1[1], s1[2], s1[3]);                                   \
    dpp16_4(rs[0], rs[1], rs[2], rs[3]);                                   \
    if ((lane & 15) == 0) {                                                \
      float* rb = redf[(RR) % 3];                                          \
      atomicAdd(&rb[0], s1[0]); atomicAdd(&rb[1], s1[1]);                  \
      atomicAdd(&rb[2], s1[2]); atomicAdd(&rb[3], s1[3]);                  \
      atomicAdd(&rb[4], rs[0]); atomicAdd(&rb[5], rs[1]);                  \
      atomicAdd(&rb[6], rs[2]); atomicAdd(&rb[7], rs[3]);                  \
    }                                                                      \
  }

  CA_ELEM(0)
  #pragma unroll 1
  for (int r = 0; r < NRND; ++r) {
    __syncthreads();
    float scn[RPR];
    {
      const float* rb = redf[r % 3];
      #pragma unroll
      for (int j = 0; j < RPR; ++j) {
        const int row = RPR*r + j;
        const float rln = fmaxf(rl_s[row] - sc_s[row]*rb[j], 0.0f);
        scn[j] = rln * RCP(rb[RPR + j] + 1e-9f);
        if (t == 0) {
          g_remainl[rowbase + row] = rln;
          g_s[rowbase + row] = scn[j];
        }
      }
    }
    if (t < 2*RPR) redf[(r + 2) % 3][t] = 0.f;
    #pragma unroll
    for (int k = 0; k < KC; ++k) {
      float acc = colacc[k];
      #pragma unroll
      for (int j = 0; j < RPR; ++j) acc = fmaf(w[j][k], scn[j], acc);
      colacc[k] = acc;
    }
    if (r + 1 < NRND) CA_ELEM(r + 1)
  }
#undef CA_ELEM
  #pragma unroll
  for (int k = 0; k < KC; ++k)
    atomicAdd(&cs_out[b*MPTS + t + TPB*k], colacc[k]);
  costacc = wsum_step1(costacc);
  if (lane == 0) cred[wave] = costacc;
  __syncthreads();
  if (t == 0)
    atomicAdd(&g_cost, cred[0] + cred[1] + cred[2] + cred[3]);
}

// C-part of level 9 (coeff 0 -> weight = p): cost only, barrier-free loop.
// Reads colsum from cbuf[9%3=0], remainr from rbuf[9&1=1].
__global__ __launch_bounds__(TPB) void k_c_last() {
  const int blk = blockIdx.x, b = blk >> 7, chunk = blk & (CHUNKS-1);
  const int t = threadIdx.x, lane = t & 63, wave = t >> 6;
  const int rowbase = b*NPTS + chunk*RPB;
  const float* __restrict__ cs_in = g_cbuf[0];
  const float* __restrict__ rr_in = g_rbuf[1];
  __shared__ float4 rowdat[RPB];
  __shared__ float  sc_s[RPB];
  __shared__ float  cred[4];
  float cx[KC], cy[KC], cz[KC], rc2[KC], pp[KC];
  #pragma unroll
  for (int k = 0; k < KC; ++k) {
    const int m = b*MPTS + t + TPB*k;
    const float4 q = g_gt4[m];
    cx[k] = q.x; cy[k] = q.y; cz[k] = q.z; rc2[k] = q.w;
    const float cs = cs_in[m], rrv = rr_in[m];
    const float ratio = fminf(rrv / (cs + 1e-9f), 1.0f);
    pp[k] = rrv*ratio;
  }
  if (t < RPB) {
    rowdat[t] = g_gen4[rowbase + t];
    sc_s[t] = g_s[rowbase + t];
  }
  __syncthreads();
  float costacc = 0.f;
  #pragma unroll 1
  for (int r = 0; r < RPB; ++r) {
    const float4 rd = rowdat[r];
    float s2 = 0.f;
    #pragma unroll
    for (int k = 0; k < KC; ++k)
      s2 = fmaf(pp[k], FSQRT(fmaxf(D2(rd, k), 1e-20f)), s2);
    costacc = fmaf(sc_s[r], s2, costacc);
  }
  costacc = wsum_step1(costacc);
  if (lane == 0) cred[wave] = costacc;
  __syncthreads();
  if (t == 0)
    atomicAdd(&g_cost, cred[0] + cred[1] + cred[2] + cred[3]);
}

__global__ void k_final(float* __restrict__ out) {
  out[0] = g_cost * (1.0f / (float)(BATCH*NPTS));
}

extern "C" void kernel_launch(void* const* d_in, const int* in_sizes, int n_in,
                              void* d_out, int out_size, void* d_ws, size_t ws_size,
                              hipStream_t stream) {
  const float* gen = (const float*)d_in[0];   // pc_gen [8,2048,3] f32
  const float* gt  = (const float*)d_in[1];   // pc_gt  [8,2048,3] f32
  float* out = (float*)d_out;

  const double L[10] = {-16384.0, -4096.0, -1024.0, -256.0, -64.0,
                        -16.0, -4.0, -1.0, -0.25, 0.0};
  float c[10];
  for (int i = 0; i < 10; ++i) c[i] = (float)(L[i] * 1.4426950408889634);

  k_init<<<64, 256, 0, stream>>>(gen, gt);
  k_a0<<<NBLK, TPB, 0, stream>>>(c[0]);
  for (int l = 0; l < 8; ++l)
    k_ca<false><<<NBLK, TPB, 0, stream>>>(c[l], c[l+1], l);
  k_ca<true><<<NBLK, TPB, 0, stream>>>(c[8], 0.f, 8);
  k_c_last<<<NBLK, TPB, 0, stream>>>();
  k_final<<<1, 1, 0, stream>>>(out);
}

// Round 15
// 378.158 us; speedup vs baseline: 1.1509x; 1.1509x over previous
//
#include <hip/hip_runtime.h>
#include <math.h>

#define BATCH 8
#define NPTS 2048
#define MPTS 2048
#define TPB 256                       // 4 waves
#define RPB 16                        // rows per block
#define KC 8                          // columns per thread: 2048/256
#define RPR 2                         // rows per round
#define NRND (RPB/RPR)                // 8 rounds
#define CHUNKS (NPTS/RPB)             // 128
#define NBLK (BATCH*CHUNKS)           // 1024

// Persistent state (re-initialized every kernel_launch -> deterministic).
// NO global atomics for colsum: each block stores its partial colsum slice to
// g_part[chunk][...]; k_red sums the 128 partials per column and folds the
// column-saturation math (pp = rr*ratio, rr update in place).
__device__ float  g_remainl[BATCH*NPTS];
__device__ float  g_s[BATCH*NPTS];
__device__ float  g_rr[BATCH*MPTS];            // remainr (in-place update)
__device__ float  g_pp[BATCH*MPTS];            // p = rr*ratio per level
__device__ float  g_part[CHUNKS][BATCH*MPTS];  // 8 MB partial colsums
__device__ float4 g_gt4[BATCH*MPTS];           // (x, y, z, |c|^2)
__device__ float4 g_gen4[BATCH*NPTS];          // (-2x, -2y, -2z, |g|^2)
__device__ float  g_cost;

#if __has_builtin(__builtin_amdgcn_exp2f)
#define EXP2(x) __builtin_amdgcn_exp2f(x)
#else
#define EXP2(x) exp2f(x)
#endif
#if __has_builtin(__builtin_amdgcn_sqrtf)
#define FSQRT(x) __builtin_amdgcn_sqrtf(x)
#else
#define FSQRT(x) sqrtf(x)
#endif
#if __has_builtin(__builtin_amdgcn_rcpf)
#define RCP(x) __builtin_amdgcn_rcpf(x)
#else
#define RCP(x) (1.0f/(x))
#endif

template<int CTRL>
__device__ __forceinline__ float dpp_add(float x) {
  const int y = __builtin_amdgcn_update_dpp(0, __float_as_int(x),
                                            CTRL, 0xF, 0xF, true);
  return x + __int_as_float(y);
}
__device__ __forceinline__ void wsum_step4(float& a, float& b, float& c, float& d) {
  a = dpp_add<0xB1>(a);  b = dpp_add<0xB1>(b);
  c = dpp_add<0xB1>(c);  d = dpp_add<0xB1>(d);
  a = dpp_add<0x4E>(a);  b = dpp_add<0x4E>(b);
  c = dpp_add<0x4E>(c);  d = dpp_add<0x4E>(d);
  a = dpp_add<0x141>(a); b = dpp_add<0x141>(b);
  c = dpp_add<0x141>(c); d = dpp_add<0x141>(d);
  a = dpp_add<0x140>(a); b = dpp_add<0x140>(b);
  c = dpp_add<0x140>(c); d = dpp_add<0x140>(d);
  a += __shfl_xor(a, 16); b += __shfl_xor(b, 16);
  c += __shfl_xor(c, 16); d += __shfl_xor(d, 16);
  a += __shfl_xor(a, 32); b += __shfl_xor(b, 32);
  c += __shfl_xor(c, 32); d += __shfl_xor(d, 32);
}
__device__ __forceinline__ void wsum_step2(float& a, float& b) {
  a = dpp_add<0xB1>(a);  b = dpp_add<0xB1>(b);
  a = dpp_add<0x4E>(a);  b = dpp_add<0x4E>(b);
  a = dpp_add<0x141>(a); b = dpp_add<0x141>(b);
  a = dpp_add<0x140>(a); b = dpp_add<0x140>(b);
  a += __shfl_xor(a, 16); b += __shfl_xor(b, 16);
  a += __shfl_xor(a, 32); b += __shfl_xor(b, 32);
}
__device__ __forceinline__ float wsum_step1(float a) {
  a = dpp_add<0xB1>(a); a = dpp_add<0x4E>(a);
  a = dpp_add<0x141>(a); a = dpp_add<0x140>(a);
  a += __shfl_xor(a, 16); a += __shfl_xor(a, 32);
  return a;
}

#define D2(rd, k) fmaf(rd.x, cx[k], fmaf(rd.y, cy[k],                      \
                   fmaf(rd.z, cz[k], rd.w + rc2[k])))

// init + point prep (SoA float4 with precomputed norms).
__global__ __launch_bounds__(256) void k_init(const float* __restrict__ gen,
                                              const float* __restrict__ gt) {
  const int i = blockIdx.x*256 + threadIdx.x;   // 64 x 256 = 16384 = B*N
  g_rr[i] = 1.f;                                // initial remainr (factorr=1)
  const float tx = gt[i*3], ty = gt[i*3+1], tz = gt[i*3+2];
  g_gt4[i] = make_float4(tx, ty, tz, tx*tx + ty*ty + tz*tz);
  const float px = gen[i*3], py = gen[i*3+1], pz = gen[i*3+2];
  g_gen4[i] = make_float4(-2.f*px, -2.f*py, -2.f*pz, px*px + py*py + pz*pz);
  if (i == 0) g_cost = 0.f;
}

// Reduce the 128 per-chunk colsum partials for each column, then do the
// column-saturation math: pp = rr*ratio; rr <- max(rr - cs*ratio, 0).
// Fixed-order sum -> deterministic (the old atomics were not).
__global__ __launch_bounds__(128) void k_red() {
  const int i = blockIdx.x*128 + threadIdx.x;   // 128 x 128 = 16384 = B*M
  float s = 0.f;
  #pragma unroll 8
  for (int c = 0; c < CHUNKS; ++c) s += g_part[c][i];
  const float rr = g_rr[i];
  const float ratio = fminf(rr / (s + 1e-9f), 1.0f);
  g_pp[i] = rr*ratio;
  g_rr[i] = fmaxf(rr - s*ratio, 0.0f);
}

// A-part of level 0 (remainl = remainr = 1): computes s(0), partial colsum(0).
__global__ __launch_bounds__(TPB) void k_a0(float c1) {
  const int blk = blockIdx.x, b = blk >> 7, chunk = blk & (CHUNKS-1);
  const int t = threadIdx.x, wave = t >> 6, lane = t & 63;
  const int rowbase = b*NPTS + chunk*RPB;
  __shared__ float4 rowdat[RPB];
  __shared__ float2 red[2][4];
  float cx[KC], cy[KC], cz[KC], rc2[KC];
  #pragma unroll
  for (int k = 0; k < KC; ++k) {
    const float4 q = g_gt4[b*MPTS + t + TPB*k];
    cx[k] = q.x; cy[k] = q.y; cz[k] = q.z; rc2[k] = q.w;
  }
  if (t < RPB) {
    rowdat[t] = g_gen4[rowbase + t];
    g_remainl[rowbase + t] = 1.0f;
  }
  __syncthreads();
  float colacc[KC];
  #pragma unroll
  for (int k = 0; k < KC; ++k) colacc[k] = 0.f;
  #pragma unroll 1
  for (int rr = 0; rr < NRND; ++rr) {
    const float4 rd0 = rowdat[2*rr+0];
    const float4 rd1 = rowdat[2*rr+1];
    float w0[KC], w1[KC];
    float s1a = 0.f, s1b = 0.f;
    #pragma unroll
    for (int k = 0; k < KC; ++k) {
      const float ea = EXP2(c1*D2(rd0, k));
      const float eb = EXP2(c1*D2(rd1, k));
      w0[k] = ea; s1a += ea;
      w1[k] = eb; s1b += eb;
    }
    wsum_step2(s1a, s1b);
    if (lane == 0) red[rr&1][wave] = make_float2(s1a, s1b);
    __syncthreads();
    const float2 v0 = red[rr&1][0], v1 = red[rr&1][1];
    const float2 v2 = red[rr&1][2], v3 = red[rr&1][3];
    const float scn0 = RCP(v0.x+v1.x+v2.x+v3.x + 1e-9f);   // remainl = 1
    const float scn1 = RCP(v0.y+v1.y+v2.y+v3.y + 1e-9f);
    if (t == 0) {
      g_s[rowbase + 2*rr + 0] = scn0;
      g_s[rowbase + 2*rr + 1] = scn1;
    }
    #pragma unroll
    for (int k = 0; k < KC; ++k)
      colacc[k] = fmaf(w0[k], scn0, fmaf(w1[k], scn1, colacc[k]));
  }
  #pragma unroll
  for (int k = 0; k < KC; ++k)
    g_part[chunk][b*MPTS + t + TPB*k] = colacc[k];   // plain store, no atomic
}

// Fused C(level l) + A(level l+1). Column stage reads pp/rrn from k_red.
// eq = exp2(cq*d2) is next level's exp; e1 = (eq^2)^2 (c1 = 4*cq exactly).
// LAST (l==8): next level coeff is 0 -> eq = 1.
template<bool LAST>
__global__ __launch_bounds__(TPB) void k_ca(float c1, float cq) {
  const int blk = blockIdx.x, b = blk >> 7, chunk = blk & (CHUNKS-1);
  const int t = threadIdx.x, wave = t >> 6, lane = t & 63;
  const int rowbase = b*NPTS + chunk*RPB;
  __shared__ float4 rowdat[RPB];
  __shared__ float  sc_s[RPB], rl_s[RPB];
  __shared__ float4 red[2][4];
  __shared__ float  cred[4];
  float cx[KC], cy[KC], cz[KC], rc2[KC], pp[KC], rrn[KC];
  #pragma unroll
  for (int k = 0; k < KC; ++k) {
    const int m = b*MPTS + t + TPB*k;
    const float4 q = g_gt4[m];
    cx[k] = q.x; cy[k] = q.y; cz[k] = q.z; rc2[k] = q.w;
    pp[k]  = g_pp[m];        // from k_red
    rrn[k] = g_rr[m];        // already post-saturation remainr
  }
  if (t < RPB) {
    rowdat[t] = g_gen4[rowbase + t];
    sc_s[t] = g_s[rowbase + t];
    rl_s[t] = g_remainl[rowbase + t];
  }
  __syncthreads();
  float colacc[KC];
  #pragma unroll
  for (int k = 0; k < KC; ++k) colacc[k] = 0.f;
  float costacc = 0.f;
  #pragma unroll 1
  for (int rr = 0; rr < NRND; ++rr) {
    const int r0 = 2*rr, r1 = r0 + 1;
    const float4 rd0 = rowdat[r0];
    const float4 rd1 = rowdat[r1];
    float w0[KC], w1[KC];
    float s1a = 0.f, rsa = 0.f, s2a = 0.f;
    float s1b = 0.f, rsb = 0.f, s2b = 0.f;
    #pragma unroll
    for (int k = 0; k < KC; ++k) {
      {
        const float d2 = D2(rd0, k);
        float e1, wq;
        if (LAST) { e1 = EXP2(c1*d2); wq = rrn[k]; }
        else { const float eq = EXP2(cq*d2); const float e2 = eq*eq;
               e1 = e2*e2; wq = eq*rrn[k]; }
        w0[k] = wq; rsa += wq;
        const float u = e1*pp[k];
        s1a += u;
        s2a = fmaf(u, FSQRT(fmaxf(d2, 1e-20f)), s2a);
      }
      {
        const float d2 = D2(rd1, k);
        float e1, wq;
        if (LAST) { e1 = EXP2(c1*d2); wq = rrn[k]; }
        else { const float eq = EXP2(cq*d2); const float e2 = eq*eq;
               e1 = e2*e2; wq = eq*rrn[k]; }
        w1[k] = wq; rsb += wq;
        const float u = e1*pp[k];
        s1b += u;
        s2b = fmaf(u, FSQRT(fmaxf(d2, 1e-20f)), s2b);
      }
    }
    costacc = fmaf(sc_s[r0], s2a, costacc);
    costacc = fmaf(sc_s[r1], s2b, costacc);
    wsum_step4(s1a, rsa, s1b, rsb);
    if (lane == 0) red[rr&1][wave] = make_float4(s1a, rsa, s1b, rsb);
    __syncthreads();
    const float4 v0 = red[rr&1][0], v1 = red[rr&1][1];
    const float4 v2 = red[rr&1][2], v3 = red[rr&1][3];
    const float s1t0 = v0.x+v1.x+v2.x+v3.x;
    const float rst0 = v0.y+v1.y+v2.y+v3.y;
    const float s1t1 = v0.z+v1.z+v2.z+v3.z;
    const float rst1 = v0.w+v1.w+v2.w+v3.w;
    const float rl0 = fmaxf(rl_s[r0] - sc_s[r0]*s1t0, 0.0f);
    const float rl1 = fmaxf(rl_s[r1] - sc_s[r1]*s1t1, 0.0f);
    const float scn0 = rl0 * RCP(rst0 + 1e-9f);
    const float scn1 = rl1 * RCP(rst1 + 1e-9f);
    if (t == 0) {
      g_remainl[rowbase + r0] = rl0;
      g_remainl[rowbase + r1] = rl1;
      g_s[rowbase + r0] = scn0;
      g_s[rowbase + r1] = scn1;
    }
    #pragma unroll
    for (int k = 0; k < KC; ++k)
      colacc[k] = fmaf(w0[k], scn0, fmaf(w1[k], scn1, colacc[k]));
  }
  #pragma unroll
  for (int k = 0; k < KC; ++k)
    g_part[chunk][b*MPTS + t + TPB*k] = colacc[k];   // plain store, no atomic
  costacc = wsum_step1(costacc);
  if (lane == 0) cred[wave] = costacc;
  __syncthreads();
  if (t == 0)
    atomicAdd(&g_cost, cred[0] + cred[1] + cred[2] + cred[3]);
}

// C-part of level 9 (coeff 0 -> weight = p = g_pp after k_red): cost only.
__global__ __launch_bounds__(TPB) void k_c_last() {
  const int blk = blockIdx.x, b = blk >> 7, chunk = blk & (CHUNKS-1);
  const int t = threadIdx.x, wave = t >> 6, lane = t & 63;
  const int rowbase = b*NPTS + chunk*RPB;
  __shared__ float4 rowdat[RPB];
  __shared__ float  sc_s[RPB];
  __shared__ float  cred[4];
  float cx[KC], cy[KC], cz[KC], rc2[KC], pp[KC];
  #pragma unroll
  for (int k = 0; k < KC; ++k) {
    const int m = b*MPTS + t + TPB*k;
    const float4 q = g_gt4[m];
    cx[k] = q.x; cy[k] = q.y; cz[k] = q.z; rc2[k] = q.w;
    pp[k] = g_pp[m];
  }
  if (t < RPB) {
    rowdat[t] = g_gen4[rowbase + t];
    sc_s[t] = g_s[rowbase + t];
  }
  __syncthreads();
  float costacc = 0.f;
  #pragma unroll 1
  for (int r = 0; r < RPB; ++r) {
    const float4 rd = rowdat[r];
    float s2 = 0.f;
    #pragma unroll
    for (int k = 0; k < KC; ++k)
      s2 = fmaf(pp[k], FSQRT(fmaxf(D2(rd, k), 1e-20f)), s2);
    costacc = fmaf(sc_s[r], s2, costacc);
  }
  costacc = wsum_step1(costacc);
  if (lane == 0) cred[wave] = costacc;
  __syncthreads();
  if (t == 0)
    atomicAdd(&g_cost, cred[0] + cred[1] + cred[2] + cred[3]);
}

__global__ void k_final(float* __restrict__ out) {
  out[0] = g_cost * (1.0f / (float)(BATCH*NPTS));
}

extern "C" void kernel_launch(void* const* d_in, const int* in_sizes, int n_in,
                              void* d_out, int out_size, void* d_ws, size_t ws_size,
                              hipStream_t stream) {
  const float* gen = (const float*)d_in[0];   // pc_gen [8,2048,3] f32
  const float* gt  = (const float*)d_in[1];   // pc_gt  [8,2048,3] f32
  float* out = (float*)d_out;

  const double L[10] = {-16384.0, -4096.0, -1024.0, -256.0, -64.0,
                        -16.0, -4.0, -1.0, -0.25, 0.0};
  float c[10];
  for (int i = 0; i < 10; ++i) c[i] = (float)(L[i] * 1.4426950408889634);

  k_init<<<64, 256, 0, stream>>>(gen, gt);
  k_a0<<<NBLK, TPB, 0, stream>>>(c[0]);
  for (int l = 0; l < 8; ++l) {
    k_red<<<128, 128, 0, stream>>>();
    k_ca<false><<<NBLK, TPB, 0, stream>>>(c[l], c[l+1]);
  }
  k_red<<<128, 128, 0, stream>>>();
  k_ca<true><<<NBLK, TPB, 0, stream>>>(c[8], 0.f);
  k_red<<<128, 128, 0, stream>>>();
  k_c_last<<<NBLK, TPB, 0, stream>>>();
  k_final<<<1, 1, 0, stream>>>(out);
}

// Round 16
// 344.631 us; speedup vs baseline: 1.2629x; 1.0973x over previous
//
#include <hip/hip_runtime.h>
#include <math.h>

#define BATCH 8
#define NPTS 2048
#define MPTS 2048
#define TPB 256                       // 4 waves
#define RPB 32                        // rows per block (R16: 16 -> 32)
#define KC 8                          // columns per thread: 2048/256
#define RPR 2                         // rows per round
#define NRND (RPB/RPR)                // 16 rounds
#define CHUNKS (NPTS/RPB)             // 64
#define NBLK (BATCH*CHUNKS)           // 512

// Persistent state (re-initialized every kernel_launch -> deterministic).
// NO global atomics for colsum: each block stores its partial colsum slice to
// g_part[chunk][...]; k_red sums the 64 partials per column and folds the
// column-saturation math: (pp, rr_new) packed as float2 in g_ppr.
__device__ float  g_remainl[BATCH*NPTS];
__device__ float  g_s[BATCH*NPTS];
__device__ float  g_rr[BATCH*MPTS];            // remainr (in-place update)
__device__ float2 g_ppr[BATCH*MPTS];           // (p, rr_new) per level
__device__ float  g_part[CHUNKS][BATCH*MPTS];  // 4 MB partial colsums
__device__ float4 g_gt4[BATCH*MPTS];           // (x, y, z, |c|^2)
__device__ float4 g_gen4[BATCH*NPTS];          // (-2x, -2y, -2z, |g|^2)
__device__ float  g_cost;

#if __has_builtin(__builtin_amdgcn_exp2f)
#define EXP2(x) __builtin_amdgcn_exp2f(x)
#else
#define EXP2(x) exp2f(x)
#endif
#if __has_builtin(__builtin_amdgcn_sqrtf)
#define FSQRT(x) __builtin_amdgcn_sqrtf(x)
#else
#define FSQRT(x) sqrtf(x)
#endif
#if __has_builtin(__builtin_amdgcn_rcpf)
#define RCP(x) __builtin_amdgcn_rcpf(x)
#else
#define RCP(x) (1.0f/(x))
#endif

template<int CTRL>
__device__ __forceinline__ float dpp_add(float x) {
  const int y = __builtin_amdgcn_update_dpp(0, __float_as_int(x),
                                            CTRL, 0xF, 0xF, true);
  return x + __int_as_float(y);
}
__device__ __forceinline__ void wsum_step4(float& a, float& b, float& c, float& d) {
  a = dpp_add<0xB1>(a);  b = dpp_add<0xB1>(b);
  c = dpp_add<0xB1>(c);  d = dpp_add<0xB1>(d);
  a = dpp_add<0x4E>(a);  b = dpp_add<0x4E>(b);
  c = dpp_add<0x4E>(c);  d = dpp_add<0x4E>(d);
  a = dpp_add<0x141>(a); b = dpp_add<0x141>(b);
  c = dpp_add<0x141>(c); d = dpp_add<0x141>(d);
  a = dpp_add<0x140>(a); b = dpp_add<0x140>(b);
  c = dpp_add<0x140>(c); d = dpp_add<0x140>(d);
  a += __shfl_xor(a, 16); b += __shfl_xor(b, 16);
  c += __shfl_xor(c, 16); d += __shfl_xor(d, 16);
  a += __shfl_xor(a, 32); b += __shfl_xor(b, 32);
  c += __shfl_xor(c, 32); d += __shfl_xor(d, 32);
}
__device__ __forceinline__ void wsum_step2(float& a, float& b) {
  a = dpp_add<0xB1>(a);  b = dpp_add<0xB1>(b);
  a = dpp_add<0x4E>(a);  b = dpp_add<0x4E>(b);
  a = dpp_add<0x141>(a); b = dpp_add<0x141>(b);
  a = dpp_add<0x140>(a); b = dpp_add<0x140>(b);
  a += __shfl_xor(a, 16); b += __shfl_xor(b, 16);
  a += __shfl_xor(a, 32); b += __shfl_xor(b, 32);
}
__device__ __forceinline__ float wsum_step1(float a) {
  a = dpp_add<0xB1>(a); a = dpp_add<0x4E>(a);
  a = dpp_add<0x141>(a); a = dpp_add<0x140>(a);
  a += __shfl_xor(a, 16); a += __shfl_xor(a, 32);
  return a;
}

#define D2(rd, k) fmaf(rd.x, cx[k], fmaf(rd.y, cy[k],                      \
                   fmaf(rd.z, cz[k], rd.w + rc2[k])))

// init + point prep (SoA float4 with precomputed norms).
__global__ __launch_bounds__(256) void k_init(const float* __restrict__ gen,
                                              const float* __restrict__ gt) {
  const int i = blockIdx.x*256 + threadIdx.x;   // 64 x 256 = 16384 = B*N
  g_rr[i] = 1.f;                                // initial remainr (factorr=1)
  const float tx = gt[i*3], ty = gt[i*3+1], tz = gt[i*3+2];
  g_gt4[i] = make_float4(tx, ty, tz, tx*tx + ty*ty + tz*tz);
  const float px = gen[i*3], py = gen[i*3+1], pz = gen[i*3+2];
  g_gen4[i] = make_float4(-2.f*px, -2.f*py, -2.f*pz, px*px + py*py + pz*pz);
  if (i == 0) g_cost = 0.f;
}

// Reduce the 64 per-chunk colsum partials per column, fold saturation math.
// Fixed-order sum -> deterministic.
__global__ __launch_bounds__(128) void k_red() {
  const int i = blockIdx.x*128 + threadIdx.x;   // 128 x 128 = 16384 = B*M
  float s = 0.f;
  #pragma unroll 8
  for (int c = 0; c < CHUNKS; ++c) s += g_part[c][i];
  const float rr = g_rr[i];
  const float ratio = fminf(rr / (s + 1e-9f), 1.0f);
  const float rrn = fmaxf(rr - s*ratio, 0.0f);
  g_ppr[i] = make_float2(rr*ratio, rrn);
  g_rr[i] = rrn;
}

// A-part of level 0 (remainl = remainr = 1): computes s(0), partial colsum(0).
__global__ __launch_bounds__(TPB) void k_a0(float c1) {
  const int blk = blockIdx.x, b = blk >> 6, chunk = blk & (CHUNKS-1);
  const int t = threadIdx.x, wave = t >> 6, lane = t & 63;
  const int rowbase = b*NPTS + chunk*RPB;
  __shared__ float4 rowdat[RPB];
  __shared__ float2 red[2][4];
  float cx[KC], cy[KC], cz[KC], rc2[KC];
  #pragma unroll
  for (int k = 0; k < KC; ++k) {
    const float4 q = g_gt4[b*MPTS + t + TPB*k];
    cx[k] = q.x; cy[k] = q.y; cz[k] = q.z; rc2[k] = q.w;
  }
  if (t < RPB) {
    rowdat[t] = g_gen4[rowbase + t];
    g_remainl[rowbase + t] = 1.0f;
  }
  __syncthreads();
  float colacc[KC];
  #pragma unroll
  for (int k = 0; k < KC; ++k) colacc[k] = 0.f;
  #pragma unroll 1
  for (int rr = 0; rr < NRND; ++rr) {
    const float4 rd0 = rowdat[2*rr+0];
    const float4 rd1 = rowdat[2*rr+1];
    float w0[KC], w1[KC];
    float s1a = 0.f, s1b = 0.f;
    #pragma unroll
    for (int k = 0; k < KC; ++k) {
      const float ea = EXP2(c1*D2(rd0, k));
      const float eb = EXP2(c1*D2(rd1, k));
      w0[k] = ea; s1a += ea;
      w1[k] = eb; s1b += eb;
    }
    wsum_step2(s1a, s1b);
    if (lane == 0) red[rr&1][wave] = make_float2(s1a, s1b);
    __syncthreads();
    const float2 v0 = red[rr&1][0], v1 = red[rr&1][1];
    const float2 v2 = red[rr&1][2], v3 = red[rr&1][3];
    const float scn0 = RCP(v0.x+v1.x+v2.x+v3.x + 1e-9f);   // remainl = 1
    const float scn1 = RCP(v0.y+v1.y+v2.y+v3.y + 1e-9f);
    if (t == 0) {
      g_s[rowbase + 2*rr + 0] = scn0;
      g_s[rowbase + 2*rr + 1] = scn1;
    }
    #pragma unroll
    for (int k = 0; k < KC; ++k)
      colacc[k] = fmaf(w0[k], scn0, fmaf(w1[k], scn1, colacc[k]));
  }
  #pragma unroll
  for (int k = 0; k < KC; ++k)
    g_part[chunk][b*MPTS + t + TPB*k] = colacc[k];   // plain store, no atomic
}

// Fused C(level l) + A(level l+1). Column stage reads (pp, rrn) from k_red.
// eq = exp2(cq*d2) is next level's exp; e1 = (eq^2)^2 (c1 = 4*cq exactly).
// LAST (l==8): next level coeff is 0 -> eq = 1.
template<bool LAST>
__global__ __launch_bounds__(TPB) void k_ca(float c1, float cq) {
  const int blk = blockIdx.x, b = blk >> 6, chunk = blk & (CHUNKS-1);
  const int t = threadIdx.x, wave = t >> 6, lane = t & 63;
  const int rowbase = b*NPTS + chunk*RPB;
  __shared__ float4 rowdat[RPB];
  __shared__ float  sc_s[RPB], rl_s[RPB];
  __shared__ float4 red[2][4];
  __shared__ float  cred[4];
  float cx[KC], cy[KC], cz[KC], rc2[KC], pp[KC], rrn[KC];
  #pragma unroll
  for (int k = 0; k < KC; ++k) {
    const int m = b*MPTS + t + TPB*k;
    const float4 q = g_gt4[m];
    cx[k] = q.x; cy[k] = q.y; cz[k] = q.z; rc2[k] = q.w;
    const float2 pr = g_ppr[m];      // from k_red
    pp[k]  = pr.x;
    rrn[k] = pr.y;
  }
  if (t < RPB) {
    rowdat[t] = g_gen4[rowbase + t];
    sc_s[t] = g_s[rowbase + t];
    rl_s[t] = g_remainl[rowbase + t];
  }
  __syncthreads();
  float colacc[KC];
  #pragma unroll
  for (int k = 0; k < KC; ++k) colacc[k] = 0.f;
  float costacc = 0.f;
  #pragma unroll 1
  for (int rr = 0; rr < NRND; ++rr) {
    const int r0 = 2*rr, r1 = r0 + 1;
    const float4 rd0 = rowdat[r0];
    const float4 rd1 = rowdat[r1];
    float w0[KC], w1[KC];
    float s1a = 0.f, rsa = 0.f, s2a = 0.f;
    float s1b = 0.f, rsb = 0.f, s2b = 0.f;
    #pragma unroll
    for (int k = 0; k < KC; ++k) {
      {
        const float d2 = D2(rd0, k);
        float e1, wq;
        if (LAST) { e1 = EXP2(c1*d2); wq = rrn[k]; }
        else { const float eq = EXP2(cq*d2); const float e2 = eq*eq;
               e1 = e2*e2; wq = eq*rrn[k]; }
        w0[k] = wq; rsa += wq;
        const float u = e1*pp[k];
        s1a += u;
        s2a = fmaf(u, FSQRT(fmaxf(d2, 1e-20f)), s2a);
      }
      {
        const float d2 = D2(rd1, k);
        float e1, wq;
        if (LAST) { e1 = EXP2(c1*d2); wq = rrn[k]; }
        else { const float eq = EXP2(cq*d2); const float e2 = eq*eq;
               e1 = e2*e2; wq = eq*rrn[k]; }
        w1[k] = wq; rsb += wq;
        const float u = e1*pp[k];
        s1b += u;
        s2b = fmaf(u, FSQRT(fmaxf(d2, 1e-20f)), s2b);
      }
    }
    costacc = fmaf(sc_s[r0], s2a, costacc);
    costacc = fmaf(sc_s[r1], s2b, costacc);
    wsum_step4(s1a, rsa, s1b, rsb);
    if (lane == 0) red[rr&1][wave] = make_float4(s1a, rsa, s1b, rsb);
    __syncthreads();
    const float4 v0 = red[rr&1][0], v1 = red[rr&1][1];
    const float4 v2 = red[rr&1][2], v3 = red[rr&1][3];
    const float s1t0 = v0.x+v1.x+v2.x+v3.x;
    const float rst0 = v0.y+v1.y+v2.y+v3.y;
    const float s1t1 = v0.z+v1.z+v2.z+v3.z;
    const float rst1 = v0.w+v1.w+v2.w+v3.w;
    const float rl0 = fmaxf(rl_s[r0] - sc_s[r0]*s1t0, 0.0f);
    const float rl1 = fmaxf(rl_s[r1] - sc_s[r1]*s1t1, 0.0f);
    const float scn0 = rl0 * RCP(rst0 + 1e-9f);
    const float scn1 = rl1 * RCP(rst1 + 1e-9f);
    if (t == 0) {
      g_remainl[rowbase + r0] = rl0;
      g_remainl[rowbase + r1] = rl1;
      g_s[rowbase + r0] = scn0;
      g_s[rowbase + r1] = scn1;
    }
    #pragma unroll
    for (int k = 0; k < KC; ++k)
      colacc[k] = fmaf(w0[k], scn0, fmaf(w1[k], scn1, colacc[k]));
  }
  #pragma unroll
  for (int k = 0; k < KC; ++k)
    g_part[chunk][b*MPTS + t + TPB*k] = colacc[k];   // plain store, no atomic
  costacc = wsum_step1(costacc);
  if (lane == 0) cred[wave] = costacc;
  __syncthreads();
  if (t == 0)
    atomicAdd(&g_cost, cred[0] + cred[1] + cred[2] + cred[3]);
}

// C-part of level 9 (coeff 0 -> weight = p from k_red): cost only.
__global__ __launch_bounds__(TPB) void k_c_last() {
  const int blk = blockIdx.x, b = blk >> 6, chunk = blk & (CHUNKS-1);
  const int t = threadIdx.x, wave = t >> 6, lane = t & 63;
  const int rowbase = b*NPTS + chunk*RPB;
  __shared__ float4 rowdat[RPB];
  __shared__ float  sc_s[RPB];
  __shared__ float  cred[4];
  float cx[KC], cy[KC], cz[KC], rc2[KC], pp[KC];
  #pragma unroll
  for (int k = 0; k < KC; ++k) {
    const int m = b*MPTS + t + TPB*k;
    const float4 q = g_gt4[m];
    cx[k] = q.x; cy[k] = q.y; cz[k] = q.z; rc2[k] = q.w;
    pp[k] = g_ppr[m].x;
  }
  if (t < RPB) {
    rowdat[t] = g_gen4[rowbase + t];
    sc_s[t] = g_s[rowbase + t];
  }
  __syncthreads();
  float costacc = 0.f;
  #pragma unroll 1
  for (int r = 0; r < RPB; ++r) {
    const float4 rd = rowdat[r];
    float s2 = 0.f;
    #pragma unroll
    for (int k = 0; k < KC; ++k)
      s2 = fmaf(pp[k], FSQRT(fmaxf(D2(rd, k), 1e-20f)), s2);
    costacc = fmaf(sc_s[r], s2, costacc);
  }
  costacc = wsum_step1(costacc);
  if (lane == 0) cred[wave] = costacc;
  __syncthreads();
  if (t == 0)
    atomicAdd(&g_cost, cred[0] + cred[1] + cred[2] + cred[3]);
}

__global__ void k_final(float* __restrict__ out) {
  out[0] = g_cost * (1.0f / (float)(BATCH*NPTS));
}

extern "C" void kernel_launch(void* const* d_in, const int* in_sizes, int n_in,
                              void* d_out, int out_size, void* d_ws, size_t ws_size,
                              hipStream_t stream) {
  const float* gen = (const float*)d_in[0];   // pc_gen [8,2048,3] f32
  const float* gt  = (const float*)d_in[1];   // pc_gt  [8,2048,3] f32
  float* out = (float*)d_out;

  const double L[10] = {-16384.0, -4096.0, -1024.0, -256.0, -64.0,
                        -16.0, -4.0, -1.0, -0.25, 0.0};
  float c[10];
  for (int i = 0; i < 10; ++i) c[i] = (float)(L[i] * 1.4426950408889634);

  k_init<<<64, 256, 0, stream>>>(gen, gt);
  k_a0<<<NBLK, TPB, 0, stream>>>(c[0]);
  for (int l = 0; l < 8; ++l) {
    k_red<<<128, 128, 0, stream>>>();
    k_ca<false><<<NBLK, TPB, 0, stream>>>(c[l], c[l+1]);
  }
  k_red<<<128, 128, 0, stream>>>();
  k_ca<true><<<NBLK, TPB, 0, stream>>>(c[8], 0.f);
  k_red<<<128, 128, 0, stream>>>();
  k_c_last<<<NBLK, TPB, 0, stream>>>();
  k_final<<<1, 1, 0, stream>>>(out);
}

// Round 17
// 310.050 us; speedup vs baseline: 1.4038x; 1.1115x over previous
//
#include <hip/hip_runtime.h>
#include <math.h>

#define BATCH 8
#define NPTS 2048
#define MPTS 2048
#define TPB 256                       // 4 waves
#define RPB 32                        // rows per block
#define KC 8                          // columns per thread: 2048/256
#define RPR 2                         // rows per round
#define NRND (RPB/RPR)                // 16 rounds
#define CHUNKS (NPTS/RPB)             // 64
#define NBLK (BATCH*CHUNKS)           // 512

// Persistent state (re-initialized every kernel_launch -> deterministic).
// colsum rotation: level l reads g_cbuf[l%3], accumulates into g_cbuf[(l+1)%3],
// zeroes g_cbuf[(l+2)%3]. remainr ping-pongs g_rbuf[l&1] -> g_rbuf[(l+1)&1].
// rr/zero global writes gated to chunk==0 (identical values across blocks).
__device__ float  g_remainl[BATCH*NPTS];
__device__ float  g_s[BATCH*NPTS];
__device__ float  g_rbuf[2][BATCH*MPTS];
__device__ float  g_cbuf[3][BATCH*MPTS];
__device__ float4 g_gt4[BATCH*MPTS];   // (x, y, z, |c|^2)
__device__ float4 g_gen4[BATCH*NPTS];  // (-2x, -2y, -2z, |g|^2)
__device__ float  g_cost;

#if __has_builtin(__builtin_amdgcn_exp2f)
#define EXP2(x) __builtin_amdgcn_exp2f(x)
#else
#define EXP2(x) exp2f(x)
#endif
#if __has_builtin(__builtin_amdgcn_sqrtf)
#define FSQRT(x) __builtin_amdgcn_sqrtf(x)
#else
#define FSQRT(x) sqrtf(x)
#endif
#if __has_builtin(__builtin_amdgcn_rcpf)
#define RCP(x) __builtin_amdgcn_rcpf(x)
#else
#define RCP(x) (1.0f/(x))
#endif

template<int CTRL>
__device__ __forceinline__ float dpp_add(float x) {
  const int y = __builtin_amdgcn_update_dpp(0, __float_as_int(x),
                                            CTRL, 0xF, 0xF, true);
  return x + __int_as_float(y);
}
__device__ __forceinline__ void wsum_step4(float& a, float& b, float& c, float& d) {
  a = dpp_add<0xB1>(a);  b = dpp_add<0xB1>(b);
  c = dpp_add<0xB1>(c);  d = dpp_add<0xB1>(d);
  a = dpp_add<0x4E>(a);  b = dpp_add<0x4E>(b);
  c = dpp_add<0x4E>(c);  d = dpp_add<0x4E>(d);
  a = dpp_add<0x141>(a); b = dpp_add<0x141>(b);
  c = dpp_add<0x141>(c); d = dpp_add<0x141>(d);
  a = dpp_add<0x140>(a); b = dpp_add<0x140>(b);
  c = dpp_add<0x140>(c); d = dpp_add<0x140>(d);
  a += __shfl_xor(a, 16); b += __shfl_xor(b, 16);
  c += __shfl_xor(c, 16); d += __shfl_xor(d, 16);
  a += __shfl_xor(a, 32); b += __shfl_xor(b, 32);
  c += __shfl_xor(c, 32); d += __shfl_xor(d, 32);
}
__device__ __forceinline__ void wsum_step2(float& a, float& b) {
  a = dpp_add<0xB1>(a);  b = dpp_add<0xB1>(b);
  a = dpp_add<0x4E>(a);  b = dpp_add<0x4E>(b);
  a = dpp_add<0x141>(a); b = dpp_add<0x141>(b);
  a = dpp_add<0x140>(a); b = dpp_add<0x140>(b);
  a += __shfl_xor(a, 16); b += __shfl_xor(b, 16);
  a += __shfl_xor(a, 32); b += __shfl_xor(b, 32);
}
__device__ __forceinline__ float wsum_step1(float a) {
  a = dpp_add<0xB1>(a); a = dpp_add<0x4E>(a);
  a = dpp_add<0x141>(a); a = dpp_add<0x140>(a);
  a += __shfl_xor(a, 16); a += __shfl_xor(a, 32);
  return a;
}

#define D2(rd, k) fmaf(rd.x, cx[k], fmaf(rd.y, cy[k],                      \
                   fmaf(rd.z, cz[k], rd.w + rc2[k])))

// init + point prep (SoA float4 with precomputed norms).
__global__ __launch_bounds__(256) void k_init(const float* __restrict__ gen,
                                              const float* __restrict__ gt) {
  const int i = blockIdx.x*256 + threadIdx.x;   // 64 x 256 = 16384 = B*N
  g_cbuf[0][i] = 0.f;
  g_cbuf[1][i] = 0.f;
  g_rbuf[0][i] = 1.f;
  const float tx = gt[i*3], ty = gt[i*3+1], tz = gt[i*3+2];
  g_gt4[i] = make_float4(tx, ty, tz, tx*tx + ty*ty + tz*tz);
  const float px = gen[i*3], py = gen[i*3+1], pz = gen[i*3+2];
  g_gen4[i] = make_float4(-2.f*px, -2.f*py, -2.f*pz, px*px + py*py + pz*pz);
  if (i == 0) g_cost = 0.f;
}

// A-part of level 0 (remainl = remainr = 1): computes s(0), colsum(0).
__global__ __launch_bounds__(TPB) void k_a0(float c1) {
  const int blk = blockIdx.x, b = blk >> 6, chunk = blk & (CHUNKS-1);
  const int t = threadIdx.x, wave = t >> 6, lane = t & 63;
  const int rowbase = b*NPTS + chunk*RPB;
  __shared__ float4 rowdat[RPB];
  __shared__ float2 red[2][4];
  float cx[KC], cy[KC], cz[KC], rc2[KC];
  #pragma unroll
  for (int k = 0; k < KC; ++k) {
    const float4 q = g_gt4[b*MPTS + t + TPB*k];
    cx[k] = q.x; cy[k] = q.y; cz[k] = q.z; rc2[k] = q.w;
  }
  if (t < RPB) {
    rowdat[t] = g_gen4[rowbase + t];
    g_remainl[rowbase + t] = 1.0f;
  }
  __syncthreads();
  float colacc[KC];
  #pragma unroll
  for (int k = 0; k < KC; ++k) colacc[k] = 0.f;
  #pragma unroll 1
  for (int rr = 0; rr < NRND; ++rr) {
    const float4 rd0 = rowdat[2*rr+0];
    const float4 rd1 = rowdat[2*rr+1];
    float w0[KC], w1[KC];
    float s1a = 0.f, s1b = 0.f;
    #pragma unroll
    for (int k = 0; k < KC; ++k) {
      const float ea = EXP2(c1*D2(rd0, k));
      const float eb = EXP2(c1*D2(rd1, k));
      w0[k] = ea; s1a += ea;
      w1[k] = eb; s1b += eb;
    }
    wsum_step2(s1a, s1b);
    if (lane == 0) red[rr&1][wave] = make_float2(s1a, s1b);
    __syncthreads();
    const float2 v0 = red[rr&1][0], v1 = red[rr&1][1];
    const float2 v2 = red[rr&1][2], v3 = red[rr&1][3];
    const float scn0 = RCP(v0.x+v1.x+v2.x+v3.x + 1e-9f);   // remainl = 1
    const float scn1 = RCP(v0.y+v1.y+v2.y+v3.y + 1e-9f);
    if (t == 0) {
      g_s[rowbase + 2*rr + 0] = scn0;
      g_s[rowbase + 2*rr + 1] = scn1;
    }
    #pragma unroll
    for (int k = 0; k < KC; ++k)
      colacc[k] = fmaf(w0[k], scn0, fmaf(w1[k], scn1, colacc[k]));
  }
  #pragma unroll
  for (int k = 0; k < KC; ++k)
    atomicAdd(&g_cbuf[0][b*MPTS + t + TPB*k], colacc[k]);   // remainr == 1
}

// Fused [k_cols(l)] + C(level l) + A(level l+1).
// eq = exp2(cq*d2) is next level's exp; e1 = (eq^2)^2 (c1 = 4*cq exactly).
// LAST (l==8): next level coeff is 0 -> eq = 1.
template<bool LAST>
__global__ __launch_bounds__(TPB) void k_ca(float c1, float cq, int l) {
  const int blk = blockIdx.x, b = blk >> 6, chunk = blk & (CHUNKS-1);
  const int t = threadIdx.x, wave = t >> 6, lane = t & 63;
  const int rowbase = b*NPTS + chunk*RPB;
  const float* __restrict__ cs_in = g_cbuf[l % 3];
  float* __restrict__ cs_out  = g_cbuf[(l+1) % 3];
  float* __restrict__ cs_zero = g_cbuf[(l+2) % 3];
  const float* __restrict__ rr_in = g_rbuf[l & 1];
  float* __restrict__ rr_out = g_rbuf[(l+1) & 1];
  __shared__ float4 rowdat[RPB];
  __shared__ float  sc_s[RPB], rl_s[RPB];
  __shared__ float4 red[2][4];
  __shared__ float  cred[4];
  // column stage + folded k_cols (global writes gated to chunk==0)
  float cx[KC], cy[KC], cz[KC], rc2[KC], pp[KC], rrn[KC];
  #pragma unroll
  for (int k = 0; k < KC; ++k) {
    const int m = b*MPTS + t + TPB*k;
    const float4 q = g_gt4[m];
    cx[k] = q.x; cy[k] = q.y; cz[k] = q.z; rc2[k] = q.w;
    const float cs = cs_in[m], rrv = rr_in[m];
    const float ratio = fminf(rrv / (cs + 1e-9f), 1.0f);
    pp[k]  = rrv*ratio;
    rrn[k] = fmaxf(rrv - cs*ratio, 0.0f);
    if (chunk == 0) { rr_out[m] = rrn[k]; cs_zero[m] = 0.0f; }
  }
  if (t < RPB) {
    rowdat[t] = g_gen4[rowbase + t];
    sc_s[t] = g_s[rowbase + t];
    rl_s[t] = g_remainl[rowbase + t];
  }
  __syncthreads();
  float colacc[KC];
  #pragma unroll
  for (int k = 0; k < KC; ++k) colacc[k] = 0.f;
  float costacc = 0.f;
  #pragma unroll 1
  for (int rr = 0; rr < NRND; ++rr) {
    const int r0 = 2*rr, r1 = r0 + 1;
    const float4 rd0 = rowdat[r0];
    const float4 rd1 = rowdat[r1];
    float w0[KC], w1[KC];
    float s1a = 0.f, rsa = 0.f, s2a = 0.f;
    float s1b = 0.f, rsb = 0.f, s2b = 0.f;
    #pragma unroll
    for (int k = 0; k < KC; ++k) {
      {
        const float d2 = D2(rd0, k);
        float e1, wq;
        if (LAST) { e1 = EXP2(c1*d2); wq = rrn[k]; }
        else { const float eq = EXP2(cq*d2); const float e2 = eq*eq;
               e1 = e2*e2; wq = eq*rrn[k]; }
        w0[k] = wq; rsa += wq;
        const float u = e1*pp[k];
        s1a += u;
        s2a = fmaf(u, FSQRT(fmaxf(d2, 1e-20f)), s2a);
      }
      {
        const float d2 = D2(rd1, k);
        float e1, wq;
        if (LAST) { e1 = EXP2(c1*d2); wq = rrn[k]; }
        else { const float eq = EXP2(cq*d2); const float e2 = eq*eq;
               e1 = e2*e2; wq = eq*rrn[k]; }
        w1[k] = wq; rsb += wq;
        const float u = e1*pp[k];
        s1b += u;
        s2b = fmaf(u, FSQRT(fmaxf(d2, 1e-20f)), s2b);
      }
    }
    costacc = fmaf(sc_s[r0], s2a, costacc);
    costacc = fmaf(sc_s[r1], s2b, costacc);
    wsum_step4(s1a, rsa, s1b, rsb);
    if (lane == 0) red[rr&1][wave] = make_float4(s1a, rsa, s1b, rsb);
    __syncthreads();
    const float4 v0 = red[rr&1][0], v1 = red[rr&1][1];
    const float4 v2 = red[rr&1][2], v3 = red[rr&1][3];
    const float s1t0 = v0.x+v1.x+v2.x+v3.x;
    const float rst0 = v0.y+v1.y+v2.y+v3.y;
    const float s1t1 = v0.z+v1.z+v2.z+v3.z;
    const float rst1 = v0.w+v1.w+v2.w+v3.w;
    const float rl0 = fmaxf(rl_s[r0] - sc_s[r0]*s1t0, 0.0f);
    const float rl1 = fmaxf(rl_s[r1] - sc_s[r1]*s1t1, 0.0f);
    const float scn0 = rl0 * RCP(rst0 + 1e-9f);
    const float scn1 = rl1 * RCP(rst1 + 1e-9f);
    if (t == 0) {
      g_remainl[rowbase + r0] = rl0;
      g_remainl[rowbase + r1] = rl1;
      g_s[rowbase + r0] = scn0;
      g_s[rowbase + r1] = scn1;
    }
    #pragma unroll
    for (int k = 0; k < KC; ++k)
      colacc[k] = fmaf(w0[k], scn0, fmaf(w1[k], scn1, colacc[k]));
  }
  #pragma unroll
  for (int k = 0; k < KC; ++k)
    atomicAdd(&cs_out[b*MPTS + t + TPB*k], colacc[k]);
  costacc = wsum_step1(costacc);
  if (lane == 0) cred[wave] = costacc;
  __syncthreads();
  if (t == 0)
    atomicAdd(&g_cost, cred[0] + cred[1] + cred[2] + cred[3]);
}

// C-part of level 9 (coeff 0 -> weight = p): cost only, barrier-free loop.
// Reads colsum from cbuf[9%3=0], remainr from rbuf[9&1=1].
__global__ __launch_bounds__(TPB) void k_c_last() {
  const int blk = blockIdx.x, b = blk >> 6, chunk = blk & (CHUNKS-1);
  const int t = threadIdx.x, wave = t >> 6, lane = t & 63;
  const int rowbase = b*NPTS + chunk*RPB;
  const float* __restrict__ cs_in = g_cbuf[0];
  const float* __restrict__ rr_in = g_rbuf[1];
  __shared__ float4 rowdat[RPB];
  __shared__ float  sc_s[RPB];
  __shared__ float  cred[4];
  float cx[KC], cy[KC], cz[KC], rc2[KC], pp[KC];
  #pragma unroll
  for (int k = 0; k < KC; ++k) {
    const int m = b*MPTS + t + TPB*k;
    const float4 q = g_gt4[m];
    cx[k] = q.x; cy[k] = q.y; cz[k] = q.z; rc2[k] = q.w;
    const float cs = cs_in[m], rrv = rr_in[m];
    const float ratio = fminf(rrv / (cs + 1e-9f), 1.0f);
    pp[k] = rrv*ratio;
  }
  if (t < RPB) {
    rowdat[t] = g_gen4[rowbase + t];
    sc_s[t] = g_s[rowbase + t];
  }
  __syncthreads();
  float costacc = 0.f;
  #pragma unroll 1
  for (int r = 0; r < RPB; ++r) {
    const float4 rd = rowdat[r];
    float s2 = 0.f;
    #pragma unroll
    for (int k = 0; k < KC; ++k)
      s2 = fmaf(pp[k], FSQRT(fmaxf(D2(rd, k), 1e-20f)), s2);
    costacc = fmaf(sc_s[r], s2, costacc);
  }
  costacc = wsum_step1(costacc);
  if (lane == 0) cred[wave] = costacc;
  __syncthreads();
  if (t == 0)
    atomicAdd(&g_cost, cred[0] + cred[1] + cred[2] + cred[3]);
}

__global__ void k_final(float* __restrict__ out) {
  out[0] = g_cost * (1.0f / (float)(BATCH*NPTS));
}

extern "C" void kernel_launch(void* const* d_in, const int* in_sizes, int n_in,
                              void* d_out, int out_size, void* d_ws, size_t ws_size,
                              hipStream_t stream) {
  const float* gen = (const float*)d_in[0];   // pc_gen [8,2048,3] f32
  const float* gt  = (const float*)d_in[1];   // pc_gt  [8,2048,3] f32
  float* out = (float*)d_out;

  const double L[10] = {-16384.0, -4096.0, -1024.0, -256.0, -64.0,
                        -16.0, -4.0, -1.0, -0.25, 0.0};
  float c[10];
  for (int i = 0; i < 10; ++i) c[i] = (float)(L[i] * 1.4426950408889634);

  k_init<<<64, 256, 0, stream>>>(gen, gt);
  k_a0<<<NBLK, TPB, 0, stream>>>(c[0]);
  for (int l = 0; l < 8; ++l)
    k_ca<false><<<NBLK, TPB, 0, stream>>>(c[l], c[l+1], l);
  k_ca<true><<<NBLK, TPB, 0, stream>>>(c[8], 0.f, 8);
  k_c_last<<<NBLK, TPB, 0, stream>>>();
  k_final<<<1, 1, 0, stream>>>(out);
}